// Round 5
// baseline (634.782 us; speedup 1.0000x reference)
//
#include <hip/hip_runtime.h>
#include <stdint.h>

typedef unsigned short ushort;
typedef __attribute__((ext_vector_type(8))) short bf16x8;
typedef __attribute__((ext_vector_type(4))) float f32x4;

// ---- bf16 helpers (bit-level) ----
__device__ __forceinline__ float b2f(ushort u) {
    return __uint_as_float(((unsigned)u) << 16);
}
__device__ __forceinline__ ushort f2b(float f) {
    unsigned u = __float_as_uint(f);
    u += 0x7fff + ((u >> 16) & 1);   // round-to-nearest-even
    return (ushort)(u >> 16);
}
__device__ __forceinline__ ushort f2b_fast(float f) {   // round-half-up (positive vals)
    return (ushort)((__float_as_uint(f) + 0x8000u) >> 16);
}

// Problem constants: B=4, N=2048, C=1024, H=16, D=64, M = B*N = 8192
#define SEQN 2048
#define EMB  1024
#define NH   16
#define HD   64
#define BHSTRIDE (SEQN * HD)   // 131072 elems per (b,h) plane

// =====================================================================
// Kernel 0: E = exp(wd*dist + bd), fp32 -> bf16.  grid = 2048 x 256.
// =====================================================================
__global__ __launch_bounds__(256) void bias_exp(
        const float* __restrict__ dist, const float* __restrict__ dw,
        const float* __restrict__ db, ushort* __restrict__ E) {
    const float wd = dw[0], bd = db[0];
    const size_t i = ((size_t)blockIdx.x * 256 + threadIdx.x) * 8;
    float4 d0 = *(const float4*)(dist + i);
    float4 d1 = *(const float4*)(dist + i + 4);
    ushort pk[8];
    pk[0] = f2b(__expf(fmaf(wd, d0.x, bd)));
    pk[1] = f2b(__expf(fmaf(wd, d0.y, bd)));
    pk[2] = f2b(__expf(fmaf(wd, d0.z, bd)));
    pk[3] = f2b(__expf(fmaf(wd, d0.w, bd)));
    pk[4] = f2b(__expf(fmaf(wd, d1.x, bd)));
    pk[5] = f2b(__expf(fmaf(wd, d1.y, bd)));
    pk[6] = f2b(__expf(fmaf(wd, d1.z, bd)));
    pk[7] = f2b(__expf(fmaf(wd, d1.w, bd)));
    *(uint4*)(E + i) = *(uint4*)pk;
}

// =====================================================================
// Shared 128x128-tile bf16 MFMA GEMM mainloop: C = A[MxK] * W[NxK]^T
// fp32 inputs converted to bf16 while staging through LDS.
// =====================================================================
__device__ __forceinline__ void gemm_mainloop_1024(
        const float* __restrict__ A, const float* __restrict__ W,
        int m0, int n0, f32x4 acc[4][4], short* As, short* Bs) {
    const int t    = threadIdx.x;
    const int lane = t & 63;
    const int wave = t >> 6;
    const int ln   = lane & 15;
    const int quad = lane >> 4;
    const int wm   = wave & 1;
    const int wn   = wave >> 1;
    const int arow = t >> 1;           // 0..127
    const int ac   = (t & 1) * 16;     // 0 or 16

    for (int i = 0; i < 4; i++)
        for (int j = 0; j < 4; j++)
            acc[i][j] = (f32x4){0.f, 0.f, 0.f, 0.f};

    for (int k0 = 0; k0 < 1024; k0 += 32) {
        const float* apf = A + (size_t)(m0 + arow) * 1024 + k0 + ac;
        const float* bpf = W + (size_t)(n0 + arow) * 1024 + k0 + ac;
        float4 fa[4], fb[4];
#pragma unroll
        for (int u = 0; u < 4; u++) { fa[u] = ((const float4*)apf)[u];
                                      fb[u] = ((const float4*)bpf)[u]; }
        ushort ta[16], tb[16];
#pragma unroll
        for (int u = 0; u < 4; u++) {
            ta[u*4+0] = f2b(fa[u].x); ta[u*4+1] = f2b(fa[u].y);
            ta[u*4+2] = f2b(fa[u].z); ta[u*4+3] = f2b(fa[u].w);
            tb[u*4+0] = f2b(fb[u].x); tb[u*4+1] = f2b(fb[u].y);
            tb[u*4+2] = f2b(fb[u].z); tb[u*4+3] = f2b(fb[u].w);
        }
        __syncthreads();
        *(uint4*)&As[arow * 40 + ac]     = *(uint4*)&ta[0];
        *(uint4*)&As[arow * 40 + ac + 8] = *(uint4*)&ta[8];
        *(uint4*)&Bs[arow * 40 + ac]     = *(uint4*)&tb[0];
        *(uint4*)&Bs[arow * 40 + ac + 8] = *(uint4*)&tb[8];
        __syncthreads();
        bf16x8 af[4], bfr[4];
#pragma unroll
        for (int i = 0; i < 4; i++)
            af[i]  = *(bf16x8*)&As[(wm * 64 + i * 16 + ln) * 40 + quad * 8];
#pragma unroll
        for (int j = 0; j < 4; j++)
            bfr[j] = *(bf16x8*)&Bs[(wn * 64 + j * 16 + ln) * 40 + quad * 8];
#pragma unroll
        for (int i = 0; i < 4; i++)
#pragma unroll
            for (int j = 0; j < 4; j++)
                acc[i][j] = __builtin_amdgcn_mfma_f32_16x16x32_bf16(
                                af[i], bfr[j], acc[i][j], 0, 0, 0);
    }
}

// =====================================================================
// Kernel 1: fused QKV projection.  grid = (M/128, 3*8)
// q,k -> [B,H,N,D] bf16 in ws; v -> TRANSPOSED [B,H,D,N] bf16 in d_out.
// =====================================================================
__global__ __launch_bounds__(256) void gemm_qkv(
        const float* __restrict__ x,
        const float* __restrict__ Wq, const float* __restrict__ Wk,
        const float* __restrict__ Wv,
        const float* __restrict__ bq, const float* __restrict__ bk,
        const float* __restrict__ bv,
        ushort* __restrict__ qb, ushort* __restrict__ kb,
        ushort* __restrict__ vT) {
    __shared__ short As[128 * 40];
    __shared__ short Bs[128 * 40];
    const int m0   = blockIdx.x * 128;
    const int nt   = blockIdx.y;           // 0..23
    const int wsel = nt >> 3;
    const int n0   = (nt & 7) * 128;
    const float* W    = (wsel == 0) ? Wq : (wsel == 1) ? Wk : Wv;
    const float* bias = (wsel == 0) ? bq : (wsel == 1) ? bk : bv;

    f32x4 acc[4][4];
    gemm_mainloop_1024(x, W, m0, n0, acc, As, Bs);

    const int t = threadIdx.x, lane = t & 63, wave = t >> 6;
    const int ln = lane & 15, quad = lane >> 4;
    const int wm = wave & 1, wn = wave >> 1;

    if (wsel < 2) {
        ushort* dst = (wsel == 0) ? qb : kb;
#pragma unroll
        for (int j = 0; j < 4; j++) {
            const int o  = n0 + wn * 64 + j * 16 + ln;     // output channel
            const float bval = bias[o];
            const int h = o >> 6, d = o & 63;
#pragma unroll
            for (int i = 0; i < 4; i++) {
                const int mg = m0 + wm * 64 + i * 16 + quad * 4;
#pragma unroll
                for (int r = 0; r < 4; r++) {
                    const int m  = mg + r;
                    const int b  = m >> 11;          // / 2048
                    const int ns = m & 2047;
                    dst[(size_t)(b * NH + h) * BHSTRIDE + (size_t)ns * HD + d] =
                        f2b(acc[i][j][r] + bval);
                }
            }
        }
    } else {
        // V transposed: vT[(b*NH+h)*BHSTRIDE + d*SEQN + n]
#pragma unroll
        for (int j = 0; j < 4; j++) {
            const int o  = n0 + wn * 64 + j * 16 + ln;
            const float bval = bias[o];
            const int h = o >> 6, d = o & 63;
#pragma unroll
            for (int i = 0; i < 4; i++) {
                const int mg = m0 + wm * 64 + i * 16 + quad * 4;
                const int b  = mg >> 11;
                const int ns = mg & 2047;           // 4-aligned, same batch
                ushort pk[4];
#pragma unroll
                for (int r = 0; r < 4; r++) pk[r] = f2b(acc[i][j][r] + bval);
                *(uint2*)&vT[(size_t)(b * NH + h) * BHSTRIDE +
                             (size_t)d * SEQN + ns] = *(uint2*)&pk[0];
            }
        }
    }
}

// =====================================================================
// Kernel 2: distance-biased attention, flash-style, barrier-free,
// TRANSPOSED score path.  grid = (N/128, H, B); 4 waves x 32 q-rows.
// S^T = K*Q^T  (mfma(kf,qf)): C-layout col=q, row=kv -> each lane holds
// 4 CONSECUTIVE kv at fixed q: vectorized P pack (b64), E loads
// (ushort4), and O^T epilogue stores (b64).
// PV: O^T = V^T * P^T (mfma(vf, pa)), P^T read as B-frags (b128).
// Output written IN-PLACE over q.
// =====================================================================
__global__ __launch_bounds__(256) void attn(
        ushort* q,                     // aliased in/out (no restrict)
        const ushort* __restrict__ k,
        const ushort* __restrict__ vT,
        const ushort* __restrict__ E) {
    __shared__ short Ps[4][32 * 72];   // per-wave P^T tile [q][kv], stride 72
    const int t = threadIdx.x, lane = t & 63, wave = t >> 6;
    const int ln = lane & 15, quad = lane >> 4;
    const int h = blockIdx.y, b = blockIdx.z;
    const int bh = b * NH + h;
    const int qw0 = blockIdx.x * 128 + wave * 32;   // this wave's 32 q-rows

    ushort* qp = q + (size_t)bh * BHSTRIDE;
    const ushort* kp = k  + (size_t)bh * BHSTRIDE;
    const ushort* vp = vT + (size_t)bh * BHSTRIDE;

    // Q fragments (B-operand; register content identical to A-layout)
    bf16x8 qf[2][2];
#pragma unroll
    for (int qi = 0; qi < 2; qi++)
#pragma unroll
        for (int ks = 0; ks < 2; ks++)
            qf[qi][ks] = *(const bf16x8*)(qp + (size_t)(qw0 + qi * 16 + ln) * HD
                                          + ks * 32 + quad * 8);

    f32x4 Ot[2][4];                    // O^T accum: col=q(ln), row=d
#pragma unroll
    for (int qi = 0; qi < 2; qi++)
#pragma unroll
        for (int nd = 0; nd < 4; nd++) Ot[qi][nd] = (f32x4){0.f, 0.f, 0.f, 0.f};
    float lsq[2] = {0.f, 0.f};         // per-lane partial softmax denominators
    short* myp = &Ps[wave][0];

    for (int kv0 = 0; kv0 < SEQN; kv0 += 64) {
        // ---- K fragments (A-operand) ----
        bf16x8 kf[4][2];
#pragma unroll
        for (int kvb = 0; kvb < 4; kvb++)
#pragma unroll
            for (int ks = 0; ks < 2; ks++)
                kf[kvb][ks] = *(const bf16x8*)(kp +
                    (size_t)(kv0 + kvb * 16 + ln) * HD + ks * 32 + quad * 8);
        // ---- E tiles: 4 consecutive kv per lane, bf16 ----
        ushort evu[2][4][4];
#pragma unroll
        for (int qi = 0; qi < 2; qi++)
#pragma unroll
            for (int kvb = 0; kvb < 4; kvb++)
                *(uint2*)&evu[qi][kvb][0] = *(const uint2*)(E +
                    (size_t)(qw0 + qi * 16 + ln) * SEQN + kv0 + kvb * 16 + quad * 4);
        // ---- S^T = K Q^T ----
        f32x4 st[2][4];
#pragma unroll
        for (int qi = 0; qi < 2; qi++)
#pragma unroll
            for (int kvb = 0; kvb < 4; kvb++) {
                f32x4 z = (f32x4){0.f, 0.f, 0.f, 0.f};
                z = __builtin_amdgcn_mfma_f32_16x16x32_bf16(kf[kvb][0], qf[qi][0], z, 0, 0, 0);
                st[qi][kvb] = __builtin_amdgcn_mfma_f32_16x16x32_bf16(kf[kvb][1], qf[qi][1], z, 0, 0, 0);
            }
        // ---- p = E * exp(s/8); pack 4 kv -> one b64 LDS write ----
#pragma unroll
        for (int qi = 0; qi < 2; qi++) {
#pragma unroll
            for (int kvb = 0; kvb < 4; kvb++) {
                float p0 = b2f(evu[qi][kvb][0]) * __expf(st[qi][kvb][0] * 0.125f);
                float p1 = b2f(evu[qi][kvb][1]) * __expf(st[qi][kvb][1] * 0.125f);
                float p2 = b2f(evu[qi][kvb][2]) * __expf(st[qi][kvb][2] * 0.125f);
                float p3 = b2f(evu[qi][kvb][3]) * __expf(st[qi][kvb][3] * 0.125f);
                lsq[qi] += (p0 + p1) + (p2 + p3);
                ushort pk[4] = {f2b_fast(p0), f2b_fast(p1), f2b_fast(p2), f2b_fast(p3)};
                *(uint2*)&myp[(qi * 16 + ln) * 72 + kvb * 16 + quad * 4] = *(uint2*)pk;
            }
        }
        // ---- V^T fragments (A-operand) ----
        bf16x8 vf[4][2];
#pragma unroll
        for (int nd = 0; nd < 4; nd++)
#pragma unroll
            for (int kc = 0; kc < 2; kc++)
                vf[nd][kc] = *(const bf16x8*)(vp +
                    (size_t)(nd * 16 + ln) * SEQN + kv0 + kc * 32 + quad * 8);
        // ---- P^T B-fragments (same-wave LDS round trip, in-order DS) ----
        bf16x8 pa[2][2];
#pragma unroll
        for (int qi = 0; qi < 2; qi++)
#pragma unroll
            for (int kc = 0; kc < 2; kc++)
                pa[qi][kc] = *(bf16x8*)&myp[(qi * 16 + ln) * 72 + kc * 32 + quad * 8];
        // ---- O^T += V^T P^T ----
#pragma unroll
        for (int qi = 0; qi < 2; qi++)
#pragma unroll
            for (int kc = 0; kc < 2; kc++)
#pragma unroll
                for (int nd = 0; nd < 4; nd++)
                    Ot[qi][nd] = __builtin_amdgcn_mfma_f32_16x16x32_bf16(
                                    vf[nd][kc], pa[qi][kc], Ot[qi][nd], 0, 0, 0);
    }

    // lsum: reduce across the 4 quads (lanes ln, ln+16, ln+32, ln+48)
    float inv[2];
#pragma unroll
    for (int qi = 0; qi < 2; qi++) {
        float v = lsq[qi];
        v += __shfl_xor(v, 16);
        v += __shfl_xor(v, 32);
        inv[qi] = 1.0f / v;
    }
    // write O^T in-place over q, [B,H,N,D]: lane holds q=ln, 4 consecutive d
#pragma unroll
    for (int qi = 0; qi < 2; qi++)
#pragma unroll
        for (int nd = 0; nd < 4; nd++) {
            ushort pk[4];
#pragma unroll
            for (int r = 0; r < 4; r++) pk[r] = f2b(Ot[qi][nd][r] * inv[qi]);
            *(uint2*)&qp[(size_t)(qw0 + qi * 16 + ln) * HD + nd * 16 + quad * 4] =
                *(uint2*)pk;
        }
}

// =====================================================================
// Kernel 3: output projection -> d_out.  grid = (M/128, 8)
// A = attn output stored [B,H,N,D] bf16 (internal); W/bias fp32.
// =====================================================================
__global__ __launch_bounds__(256) void gemm_out(
        const ushort* ao, const float* __restrict__ W,
        const float* __restrict__ bias, float* __restrict__ out) {
    __shared__ short As[128 * 40];
    __shared__ short Bs[128 * 40];
    const int m0 = blockIdx.x * 128;
    const int n0 = blockIdx.y * 128;
    const int t    = threadIdx.x;
    const int lane = t & 63;
    const int wave = t >> 6;
    const int ln   = lane & 15;
    const int quad = lane >> 4;
    const int wm   = wave & 1;
    const int wn   = wave >> 1;
    const int arow = t >> 1;
    const int ac   = (t & 1) * 16;

    const int mrow = m0 + arow;
    const int ab   = mrow >> 11;          // batch
    const int an   = mrow & 2047;         // seq pos
    const ushort* abase = ao + ((size_t)ab << 21) + (size_t)an * HD;

    f32x4 acc[4][4];
    for (int i = 0; i < 4; i++)
        for (int j = 0; j < 4; j++)
            acc[i][j] = (f32x4){0.f, 0.f, 0.f, 0.f};

    for (int k0 = 0; k0 < 1024; k0 += 32) {
        const int kk = k0 + ac;
        const int hh = kk >> 6, d0 = kk & 63;
        const ushort* ap = abase + ((size_t)hh << 17) + d0;
        uint4 sa0 = *(const uint4*)ap;
        uint4 sa1 = *(const uint4*)(ap + 8);
        const float* bpf = W + (size_t)(n0 + arow) * 1024 + kk;
        float4 fb[4];
#pragma unroll
        for (int u = 0; u < 4; u++) fb[u] = ((const float4*)bpf)[u];
        ushort tb[16];
#pragma unroll
        for (int u = 0; u < 4; u++) {
            tb[u*4+0] = f2b(fb[u].x); tb[u*4+1] = f2b(fb[u].y);
            tb[u*4+2] = f2b(fb[u].z); tb[u*4+3] = f2b(fb[u].w);
        }
        __syncthreads();
        *(uint4*)&As[arow * 40 + ac]     = sa0;
        *(uint4*)&As[arow * 40 + ac + 8] = sa1;
        *(uint4*)&Bs[arow * 40 + ac]     = *(uint4*)&tb[0];
        *(uint4*)&Bs[arow * 40 + ac + 8] = *(uint4*)&tb[8];
        __syncthreads();
        bf16x8 af[4], bfr[4];
#pragma unroll
        for (int i = 0; i < 4; i++)
            af[i]  = *(bf16x8*)&As[(wm * 64 + i * 16 + ln) * 40 + quad * 8];
#pragma unroll
        for (int j = 0; j < 4; j++)
            bfr[j] = *(bf16x8*)&Bs[(wn * 64 + j * 16 + ln) * 40 + quad * 8];
#pragma unroll
        for (int i = 0; i < 4; i++)
#pragma unroll
            for (int j = 0; j < 4; j++)
                acc[i][j] = __builtin_amdgcn_mfma_f32_16x16x32_bf16(
                                af[i], bfr[j], acc[i][j], 0, 0, 0);
    }

#pragma unroll
    for (int j = 0; j < 4; j++) {
        const int o = n0 + wn * 64 + j * 16 + ln;
        const float bval = bias[o];
#pragma unroll
        for (int i = 0; i < 4; i++) {
            const int mg = m0 + wm * 64 + i * 16 + quad * 4;
#pragma unroll
            for (int r = 0; r < 4; r++)
                out[(size_t)(mg + r) * EMB + o] = acc[i][j][r] + bval;
        }
    }
}

// =====================================================================
extern "C" void kernel_launch(void* const* d_in, const int* in_sizes, int n_in,
                              void* d_out, int out_size, void* d_ws, size_t ws_size,
                              hipStream_t stream) {
    const float* x    = (const float*)d_in[0];
    const float* dist = (const float*)d_in[1];
    const float* Wq   = (const float*)d_in[2];
    const float* bq   = (const float*)d_in[3];
    const float* Wk   = (const float*)d_in[4];
    const float* bk   = (const float*)d_in[5];
    const float* Wv   = (const float*)d_in[6];
    const float* bv   = (const float*)d_in[7];
    const float* Wo   = (const float*)d_in[8];
    const float* bo   = (const float*)d_in[9];
    const float* dw   = (const float*)d_in[10];
    const float* db   = (const float*)d_in[11];

    const size_t PLANE = (size_t)8192 * 1024;   // elems per [M,C] bf16 buffer
    ushort* qb = (ushort*)d_ws;                 // [B,H,N,D] bf16, later attn out
    ushort* kb = qb + PLANE;                    // [B,H,N,D] bf16
    // d_out is fp32 [8192,1024] = 33.6 MB; use as scratch before gemm_out:
    ushort* vT = (ushort*)d_out;                // [B,H,D,N] bf16 (16.8 MB)
    ushort* Eb = vT + PLANE;                    // [N,N] bf16 exp-bias (8.4 MB)

    dim3 blk(256);
    bias_exp<<<dim3(2048),      blk, 0, stream>>>(dist, dw, db, Eb);
    gemm_qkv<<<dim3(64, 24),    blk, 0, stream>>>(x, Wq, Wk, Wv, bq, bk, bv,
                                                  qb, kb, vT);
    attn    <<<dim3(16, 16, 4), blk, 0, stream>>>(qb, kb, vT, Eb);
    gemm_out<<<dim3(64, 8),     blk, 0, stream>>>(qb, Wo, bo, (float*)d_out);
}

// Round 6
// 559.627 us; speedup vs baseline: 1.1343x; 1.1343x over previous
//
#include <hip/hip_runtime.h>
#include <stdint.h>

typedef unsigned short ushort;
typedef __attribute__((ext_vector_type(8))) short bf16x8;
typedef __attribute__((ext_vector_type(4))) float f32x4;

// ---- bf16 helpers (bit-level) ----
__device__ __forceinline__ float b2f(ushort u) {
    return __uint_as_float(((unsigned)u) << 16);
}
__device__ __forceinline__ ushort f2b(float f) {
    unsigned u = __float_as_uint(f);
    u += 0x7fff + ((u >> 16) & 1);   // round-to-nearest-even
    return (ushort)(u >> 16);
}
__device__ __forceinline__ ushort f2b_fast(float f) {   // round-half-up (positive vals)
    return (ushort)((__float_as_uint(f) + 0x8000u) >> 16);
}

// Problem constants: B=4, N=2048, C=1024, H=16, D=64, M = B*N = 8192
#define SEQN 2048
#define EMB  1024
#define NH   16
#define HD   64
#define BHSTRIDE (SEQN * HD)   // 131072 elems per (b,h) plane

// =====================================================================
// Kernel 0: E = exp(wd*dist + bd), fp32 -> bf16.  grid = 2048 x 256.
// =====================================================================
__global__ __launch_bounds__(256) void bias_exp(
        const float* __restrict__ dist, const float* __restrict__ dw,
        const float* __restrict__ db, ushort* __restrict__ E) {
    const float wd = dw[0], bd = db[0];
    const size_t i = ((size_t)blockIdx.x * 256 + threadIdx.x) * 8;
    float4 d0 = *(const float4*)(dist + i);
    float4 d1 = *(const float4*)(dist + i + 4);
    ushort pk[8];
    pk[0] = f2b(__expf(fmaf(wd, d0.x, bd)));
    pk[1] = f2b(__expf(fmaf(wd, d0.y, bd)));
    pk[2] = f2b(__expf(fmaf(wd, d0.z, bd)));
    pk[3] = f2b(__expf(fmaf(wd, d0.w, bd)));
    pk[4] = f2b(__expf(fmaf(wd, d1.x, bd)));
    pk[5] = f2b(__expf(fmaf(wd, d1.y, bd)));
    pk[6] = f2b(__expf(fmaf(wd, d1.z, bd)));
    pk[7] = f2b(__expf(fmaf(wd, d1.w, bd)));
    *(uint4*)(E + i) = *(uint4*)pk;
}

// =====================================================================
// Shared 128x128-tile bf16 MFMA GEMM mainloop: C = A[MxK] * W[NxK]^T
// fp32 inputs converted to bf16 while staging through LDS.
// =====================================================================
__device__ __forceinline__ void gemm_mainloop_1024(
        const float* __restrict__ A, const float* __restrict__ W,
        int m0, int n0, f32x4 acc[4][4], short* As, short* Bs) {
    const int t    = threadIdx.x;
    const int lane = t & 63;
    const int wave = t >> 6;
    const int ln   = lane & 15;
    const int quad = lane >> 4;
    const int wm   = wave & 1;
    const int wn   = wave >> 1;
    const int arow = t >> 1;           // 0..127
    const int ac   = (t & 1) * 16;     // 0 or 16

    for (int i = 0; i < 4; i++)
        for (int j = 0; j < 4; j++)
            acc[i][j] = (f32x4){0.f, 0.f, 0.f, 0.f};

    for (int k0 = 0; k0 < 1024; k0 += 32) {
        const float* apf = A + (size_t)(m0 + arow) * 1024 + k0 + ac;
        const float* bpf = W + (size_t)(n0 + arow) * 1024 + k0 + ac;
        float4 fa[4], fb[4];
#pragma unroll
        for (int u = 0; u < 4; u++) { fa[u] = ((const float4*)apf)[u];
                                      fb[u] = ((const float4*)bpf)[u]; }
        ushort ta[16], tb[16];
#pragma unroll
        for (int u = 0; u < 4; u++) {
            ta[u*4+0] = f2b(fa[u].x); ta[u*4+1] = f2b(fa[u].y);
            ta[u*4+2] = f2b(fa[u].z); ta[u*4+3] = f2b(fa[u].w);
            tb[u*4+0] = f2b(fb[u].x); tb[u*4+1] = f2b(fb[u].y);
            tb[u*4+2] = f2b(fb[u].z); tb[u*4+3] = f2b(fb[u].w);
        }
        __syncthreads();
        *(uint4*)&As[arow * 40 + ac]     = *(uint4*)&ta[0];
        *(uint4*)&As[arow * 40 + ac + 8] = *(uint4*)&ta[8];
        *(uint4*)&Bs[arow * 40 + ac]     = *(uint4*)&tb[0];
        *(uint4*)&Bs[arow * 40 + ac + 8] = *(uint4*)&tb[8];
        __syncthreads();
        bf16x8 af[4], bfr[4];
#pragma unroll
        for (int i = 0; i < 4; i++)
            af[i]  = *(bf16x8*)&As[(wm * 64 + i * 16 + ln) * 40 + quad * 8];
#pragma unroll
        for (int j = 0; j < 4; j++)
            bfr[j] = *(bf16x8*)&Bs[(wn * 64 + j * 16 + ln) * 40 + quad * 8];
#pragma unroll
        for (int i = 0; i < 4; i++)
#pragma unroll
            for (int j = 0; j < 4; j++)
                acc[i][j] = __builtin_amdgcn_mfma_f32_16x16x32_bf16(
                                af[i], bfr[j], acc[i][j], 0, 0, 0);
    }
}

// =====================================================================
// Kernel 1: fused QKV projection.  grid = (M/128, 3*8)
// q (PRE-SCALED by 1/8), k -> [B,H,N,D] bf16 in ws;
// v -> TRANSPOSED [B,H,D,N] bf16 in d_out scratch.
// =====================================================================
__global__ __launch_bounds__(256) void gemm_qkv(
        const float* __restrict__ x,
        const float* __restrict__ Wq, const float* __restrict__ Wk,
        const float* __restrict__ Wv,
        const float* __restrict__ bq, const float* __restrict__ bk,
        const float* __restrict__ bv,
        ushort* __restrict__ qb, ushort* __restrict__ kb,
        ushort* __restrict__ vT) {
    __shared__ short As[128 * 40];
    __shared__ short Bs[128 * 40];
    const int m0   = blockIdx.x * 128;
    const int nt   = blockIdx.y;           // 0..23
    const int wsel = nt >> 3;
    const int n0   = (nt & 7) * 128;
    const float* W    = (wsel == 0) ? Wq : (wsel == 1) ? Wk : Wv;
    const float* bias = (wsel == 0) ? bq : (wsel == 1) ? bk : bv;

    f32x4 acc[4][4];
    gemm_mainloop_1024(x, W, m0, n0, acc, As, Bs);

    const int t = threadIdx.x, lane = t & 63, wave = t >> 6;
    const int ln = lane & 15, quad = lane >> 4;
    const int wm = wave & 1, wn = wave >> 1;

    if (wsel < 2) {
        ushort* dst = (wsel == 0) ? qb : kb;
        const float scale = (wsel == 0) ? 0.125f : 1.0f;   // q pre-scaled
#pragma unroll
        for (int j = 0; j < 4; j++) {
            const int o  = n0 + wn * 64 + j * 16 + ln;     // output channel
            const float bval = bias[o];
            const int h = o >> 6, d = o & 63;
#pragma unroll
            for (int i = 0; i < 4; i++) {
                const int mg = m0 + wm * 64 + i * 16 + quad * 4;
#pragma unroll
                for (int r = 0; r < 4; r++) {
                    const int m  = mg + r;
                    const int b  = m >> 11;          // / 2048
                    const int ns = m & 2047;
                    dst[(size_t)(b * NH + h) * BHSTRIDE + (size_t)ns * HD + d] =
                        f2b((acc[i][j][r] + bval) * scale);
                }
            }
        }
    } else {
        // V transposed: vT[(b*NH+h)*BHSTRIDE + d*SEQN + n]
#pragma unroll
        for (int j = 0; j < 4; j++) {
            const int o  = n0 + wn * 64 + j * 16 + ln;
            const float bval = bias[o];
            const int h = o >> 6, d = o & 63;
#pragma unroll
            for (int i = 0; i < 4; i++) {
                const int mg = m0 + wm * 64 + i * 16 + quad * 4;
                const int b  = mg >> 11;
                const int ns = mg & 2047;           // 4-aligned, same batch
                ushort pk[4];
#pragma unroll
                for (int r = 0; r < 4; r++) pk[r] = f2b(acc[i][j][r] + bval);
                *(uint2*)&vT[(size_t)(b * NH + h) * BHSTRIDE +
                             (size_t)d * SEQN + ns] = *(uint2*)&pk[0];
            }
        }
    }
}

// =====================================================================
// Kernel 2: distance-biased attention, flash-style, barrier-free,
// SOFTWARE-PIPELINED.  grid = (N/128, H, B); 4 waves x 32 q-rows,
// kv-tile 64.  Round-4 data orientation (coalesced E/P paths).
// K fragments double-buffered one iteration ahead (wrap prefetch);
// V fragments + E values issued at iteration top so their latency
// hides under the QK MFMAs.  Output written IN-PLACE over q.
// q is pre-scaled by 1/8, so p = E * exp(s) directly.
// =====================================================================
__global__ __launch_bounds__(256) void attn(
        ushort* q,                     // aliased in/out (no restrict)
        const ushort* __restrict__ k,
        const ushort* __restrict__ vT,
        const ushort* __restrict__ E) {
    __shared__ short Ps[4][32 * 72];   // per-wave P tile [q-row][kv], stride 72
    const int t = threadIdx.x, lane = t & 63, wave = t >> 6;
    const int ln = lane & 15, quad = lane >> 4;
    const int h = blockIdx.y, b = blockIdx.z;
    const int bh = b * NH + h;
    const int qw0 = blockIdx.x * 128 + wave * 32;   // this wave's 32 q-rows

    ushort* qp = q + (size_t)bh * BHSTRIDE;
    const ushort* kp = k  + (size_t)bh * BHSTRIDE;
    const ushort* vp = vT + (size_t)bh * BHSTRIDE;

    // Q fragments (A-operand): registers for the whole kv loop
    bf16x8 qf[2][2];
#pragma unroll
    for (int qi = 0; qi < 2; qi++)
#pragma unroll
        for (int ks = 0; ks < 2; ks++)
            qf[qi][ks] = *(const bf16x8*)(qp + (size_t)(qw0 + qi * 16 + ln) * HD
                                          + ks * 32 + quad * 8);

    f32x4 O[2][4];
#pragma unroll
    for (int qi = 0; qi < 2; qi++)
#pragma unroll
        for (int nd = 0; nd < 4; nd++) O[qi][nd] = (f32x4){0.f, 0.f, 0.f, 0.f};
    float lsum[2][4] = {{0.f,0.f,0.f,0.f},{0.f,0.f,0.f,0.f}};
    short* myp = &Ps[wave][0];

    // ---- preload iteration-0 K fragments ----
    bf16x8 kfA[4][2];
#pragma unroll
    for (int kvb = 0; kvb < 4; kvb++)
#pragma unroll
        for (int ks = 0; ks < 2; ks++)
            kfA[kvb][ks] = *(const bf16x8*)(kp +
                (size_t)(kvb * 16 + ln) * HD + ks * 32 + quad * 8);

    for (int kt = 0; kt < 32; kt++) {
        const int kv0 = kt * 64;
        const int kvn = (kv0 + 64) & 2047;      // wrap: last prefetch harmless
        // ---- current V fragments (B-op for PV): early issue ----
        bf16x8 vf[4][2];
#pragma unroll
        for (int nd = 0; nd < 4; nd++)
#pragma unroll
            for (int kc = 0; kc < 2; kc++)
                vf[nd][kc] = *(const bf16x8*)(vp +
                    (size_t)(nd * 16 + ln) * SEQN + kv0 + kc * 32 + quad * 8);
        // ---- current E values (coalesced 32B/quad-row): early issue ----
        ushort ev[2][4][4];
#pragma unroll
        for (int qi = 0; qi < 2; qi++)
#pragma unroll
            for (int kvb = 0; kvb < 4; kvb++)
#pragma unroll
                for (int r = 0; r < 4; r++)
                    ev[qi][kvb][r] = E[(size_t)(qw0 + qi * 16 + quad * 4 + r) * SEQN
                                       + kv0 + kvb * 16 + ln];
        // ---- prefetch next iteration's K fragments ----
        bf16x8 kfB[4][2];
#pragma unroll
        for (int kvb = 0; kvb < 4; kvb++)
#pragma unroll
            for (int ks = 0; ks < 2; ks++)
                kfB[kvb][ks] = *(const bf16x8*)(kp +
                    (size_t)(kvn + kvb * 16 + ln) * HD + ks * 32 + quad * 8);
        // ---- S = Q K^T  (uses kfA, loaded one iteration ago) ----
        f32x4 s[2][4];
#pragma unroll
        for (int qi = 0; qi < 2; qi++)
#pragma unroll
            for (int kvb = 0; kvb < 4; kvb++) {
                f32x4 z = (f32x4){0.f, 0.f, 0.f, 0.f};
                z = __builtin_amdgcn_mfma_f32_16x16x32_bf16(qf[qi][0], kfA[kvb][0], z, 0, 0, 0);
                s[qi][kvb] = __builtin_amdgcn_mfma_f32_16x16x32_bf16(qf[qi][1], kfA[kvb][1], z, 0, 0, 0);
            }
        // ---- p = E * exp(s); pack to per-wave LDS (C -> A layout) ----
#pragma unroll
        for (int qi = 0; qi < 2; qi++)
#pragma unroll
            for (int kvb = 0; kvb < 4; kvb++)
#pragma unroll
                for (int r = 0; r < 4; r++) {
                    const float p = b2f(ev[qi][kvb][r]) * __expf(s[qi][kvb][r]);
                    lsum[qi][r] += p;
                    myp[(qi * 16 + quad * 4 + r) * 72 + kvb * 16 + ln] =
                        (short)f2b_fast(p);
                }
        // ---- P A-fragments (same-wave LDS round trip, in-order DS) ----
        bf16x8 pa[2][2];
#pragma unroll
        for (int qi = 0; qi < 2; qi++)
#pragma unroll
            for (int kc = 0; kc < 2; kc++)
                pa[qi][kc] = *(bf16x8*)&myp[(qi * 16 + ln) * 72 + kc * 32 + quad * 8];
        // ---- O += P V ----
#pragma unroll
        for (int qi = 0; qi < 2; qi++)
#pragma unroll
            for (int kc = 0; kc < 2; kc++)
#pragma unroll
                for (int nd = 0; nd < 4; nd++)
                    O[qi][nd] = __builtin_amdgcn_mfma_f32_16x16x32_bf16(
                                    pa[qi][kc], vf[nd][kc], O[qi][nd], 0, 0, 0);
        // ---- rotate K buffers ----
#pragma unroll
        for (int kvb = 0; kvb < 4; kvb++)
#pragma unroll
            for (int ks = 0; ks < 2; ks++)
                kfA[kvb][ks] = kfB[kvb][ks];
    }

    // row-sum reduce across the 16 lanes of each quad-row group
#pragma unroll
    for (int qi = 0; qi < 2; qi++)
#pragma unroll
        for (int r = 0; r < 4; r++) {
            float v = lsum[qi][r];
            v += __shfl_xor(v, 1, 16);
            v += __shfl_xor(v, 2, 16);
            v += __shfl_xor(v, 4, 16);
            v += __shfl_xor(v, 8, 16);
            lsum[qi][r] = 1.0f / v;
        }
    // write output in-place over q, [B,H,N,D] layout
#pragma unroll
    for (int qi = 0; qi < 2; qi++)
#pragma unroll
        for (int nd = 0; nd < 4; nd++)
#pragma unroll
            for (int r = 0; r < 4; r++) {
                qp[(size_t)(qw0 + qi * 16 + quad * 4 + r) * HD + nd * 16 + ln] =
                    f2b(O[qi][nd][r] * lsum[qi][r]);
            }
}

// =====================================================================
// Kernel 3: output projection -> d_out.  grid = (M/128, 8)
// A = attn output stored [B,H,N,D] bf16 (internal); W/bias fp32.
// =====================================================================
__global__ __launch_bounds__(256) void gemm_out(
        const ushort* ao, const float* __restrict__ W,
        const float* __restrict__ bias, float* __restrict__ out) {
    __shared__ short As[128 * 40];
    __shared__ short Bs[128 * 40];
    const int m0 = blockIdx.x * 128;
    const int n0 = blockIdx.y * 128;
    const int t    = threadIdx.x;
    const int lane = t & 63;
    const int wave = t >> 6;
    const int ln   = lane & 15;
    const int quad = lane >> 4;
    const int wm   = wave & 1;
    const int wn   = wave >> 1;
    const int arow = t >> 1;
    const int ac   = (t & 1) * 16;

    const int mrow = m0 + arow;
    const int ab   = mrow >> 11;          // batch
    const int an   = mrow & 2047;         // seq pos
    const ushort* abase = ao + ((size_t)ab << 21) + (size_t)an * HD;

    f32x4 acc[4][4];
    for (int i = 0; i < 4; i++)
        for (int j = 0; j < 4; j++)
            acc[i][j] = (f32x4){0.f, 0.f, 0.f, 0.f};

    for (int k0 = 0; k0 < 1024; k0 += 32) {
        const int kk = k0 + ac;
        const int hh = kk >> 6, d0 = kk & 63;
        const ushort* ap = abase + ((size_t)hh << 17) + d0;
        uint4 sa0 = *(const uint4*)ap;
        uint4 sa1 = *(const uint4*)(ap + 8);
        const float* bpf = W + (size_t)(n0 + arow) * 1024 + kk;
        float4 fb[4];
#pragma unroll
        for (int u = 0; u < 4; u++) fb[u] = ((const float4*)bpf)[u];
        ushort tb[16];
#pragma unroll
        for (int u = 0; u < 4; u++) {
            tb[u*4+0] = f2b(fb[u].x); tb[u*4+1] = f2b(fb[u].y);
            tb[u*4+2] = f2b(fb[u].z); tb[u*4+3] = f2b(fb[u].w);
        }
        __syncthreads();
        *(uint4*)&As[arow * 40 + ac]     = sa0;
        *(uint4*)&As[arow * 40 + ac + 8] = sa1;
        *(uint4*)&Bs[arow * 40 + ac]     = *(uint4*)&tb[0];
        *(uint4*)&Bs[arow * 40 + ac + 8] = *(uint4*)&tb[8];
        __syncthreads();
        bf16x8 af[4], bfr[4];
#pragma unroll
        for (int i = 0; i < 4; i++)
            af[i]  = *(bf16x8*)&As[(wm * 64 + i * 16 + ln) * 40 + quad * 8];
#pragma unroll
        for (int j = 0; j < 4; j++)
            bfr[j] = *(bf16x8*)&Bs[(wn * 64 + j * 16 + ln) * 40 + quad * 8];
#pragma unroll
        for (int i = 0; i < 4; i++)
#pragma unroll
            for (int j = 0; j < 4; j++)
                acc[i][j] = __builtin_amdgcn_mfma_f32_16x16x32_bf16(
                                af[i], bfr[j], acc[i][j], 0, 0, 0);
    }

#pragma unroll
    for (int j = 0; j < 4; j++) {
        const int o = n0 + wn * 64 + j * 16 + ln;
        const float bval = bias[o];
#pragma unroll
        for (int i = 0; i < 4; i++) {
            const int mg = m0 + wm * 64 + i * 16 + quad * 4;
#pragma unroll
            for (int r = 0; r < 4; r++)
                out[(size_t)(mg + r) * EMB + o] = acc[i][j][r] + bval;
        }
    }
}

// =====================================================================
extern "C" void kernel_launch(void* const* d_in, const int* in_sizes, int n_in,
                              void* d_out, int out_size, void* d_ws, size_t ws_size,
                              hipStream_t stream) {
    const float* x    = (const float*)d_in[0];
    const float* dist = (const float*)d_in[1];
    const float* Wq   = (const float*)d_in[2];
    const float* bq   = (const float*)d_in[3];
    const float* Wk   = (const float*)d_in[4];
    const float* bk   = (const float*)d_in[5];
    const float* Wv   = (const float*)d_in[6];
    const float* bv   = (const float*)d_in[7];
    const float* Wo   = (const float*)d_in[8];
    const float* bo   = (const float*)d_in[9];
    const float* dw   = (const float*)d_in[10];
    const float* db   = (const float*)d_in[11];

    const size_t PLANE = (size_t)8192 * 1024;   // elems per [M,C] bf16 buffer
    ushort* qb = (ushort*)d_ws;                 // [B,H,N,D] bf16, later attn out
    ushort* kb = qb + PLANE;                    // [B,H,N,D] bf16
    // d_out is fp32 [8192,1024] = 33.6 MB; use as scratch before gemm_out:
    ushort* vT = (ushort*)d_out;                // [B,H,D,N] bf16 (16.8 MB)
    ushort* Eb = vT + PLANE;                    // [N,N] bf16 exp-bias (8.4 MB)

    dim3 blk(256);
    bias_exp<<<dim3(2048),      blk, 0, stream>>>(dist, dw, db, Eb);
    gemm_qkv<<<dim3(64, 24),    blk, 0, stream>>>(x, Wq, Wk, Wv, bq, bk, bv,
                                                  qb, kb, vT);
    attn    <<<dim3(16, 16, 4), blk, 0, stream>>>(qb, kb, vT, Eb);
    gemm_out<<<dim3(64, 8),     blk, 0, stream>>>(qb, Wo, bo, (float*)d_out);
}

// Round 7
// 434.267 us; speedup vs baseline: 1.4617x; 1.2887x over previous
//
#include <hip/hip_runtime.h>
#include <stdint.h>

typedef unsigned short ushort;
typedef __attribute__((ext_vector_type(8))) short bf16x8;
typedef __attribute__((ext_vector_type(4))) float f32x4;

// ---- bf16 helpers (bit-level) ----
__device__ __forceinline__ float b2f(ushort u) {
    return __uint_as_float(((unsigned)u) << 16);
}
__device__ __forceinline__ ushort f2b(float f) {
    unsigned u = __float_as_uint(f);
    u += 0x7fff + ((u >> 16) & 1);   // round-to-nearest-even
    return (ushort)(u >> 16);
}
__device__ __forceinline__ ushort f2b_fast(float f) {   // round-half-up (positive vals)
    return (ushort)((__float_as_uint(f) + 0x8000u) >> 16);
}

// Problem constants: B=4, N=2048, C=1024, H=16, D=64, M = B*N = 8192
#define SEQN 2048
#define EMB  1024
#define NH   16
#define HD   64
#define BHSTRIDE (SEQN * HD)   // 131072 elems per (b,h) plane

// =====================================================================
// Kernel 0: permuted bias table.
// E_perm[qt][kv][q'] = exp(wd*dist[qt*16+q'][kv] + bd), bf16.
// Layout matches attn's MFMA C-layout consumption: lane (quad,ln) at
// (qi,kvb) reads uint2 at qt*32768 + kv*16 + quad*4 -> coalesced.
// grid = (8, 128): block = 256 kv-columns x one 16-row q-tile.
// =====================================================================
__global__ __launch_bounds__(256) void bias_exp_perm(
        const float* __restrict__ dist, const float* __restrict__ dw,
        const float* __restrict__ db, ushort* __restrict__ E) {
    const float wd = dw[0], bd = db[0];
    const int kv = blockIdx.x * 256 + threadIdx.x;
    const int qt = blockIdx.y;
    ushort pk[16];
#pragma unroll
    for (int qq = 0; qq < 16; qq++)
        pk[qq] = f2b(__expf(fmaf(wd, dist[(size_t)(qt * 16 + qq) * SEQN + kv], bd)));
    ushort* dst = E + ((size_t)qt << 15) + (size_t)kv * 16;
    *(uint4*)dst       = *(uint4*)&pk[0];
    *(uint4*)(dst + 8) = *(uint4*)&pk[8];
}

// =====================================================================
// Shared 128x128-tile bf16 MFMA GEMM mainloop: C = A[MxK] * W[NxK]^T
// fp32 inputs converted to bf16 while staging through LDS.
// =====================================================================
__device__ __forceinline__ void gemm_mainloop_1024(
        const float* __restrict__ A, const float* __restrict__ W,
        int m0, int n0, f32x4 acc[4][4], short* As, short* Bs) {
    const int t    = threadIdx.x;
    const int lane = t & 63;
    const int wave = t >> 6;
    const int ln   = lane & 15;
    const int quad = lane >> 4;
    const int wm   = wave & 1;
    const int wn   = wave >> 1;
    const int arow = t >> 1;           // 0..127
    const int ac   = (t & 1) * 16;     // 0 or 16

    for (int i = 0; i < 4; i++)
        for (int j = 0; j < 4; j++)
            acc[i][j] = (f32x4){0.f, 0.f, 0.f, 0.f};

    for (int k0 = 0; k0 < 1024; k0 += 32) {
        const float* apf = A + (size_t)(m0 + arow) * 1024 + k0 + ac;
        const float* bpf = W + (size_t)(n0 + arow) * 1024 + k0 + ac;
        float4 fa[4], fb[4];
#pragma unroll
        for (int u = 0; u < 4; u++) { fa[u] = ((const float4*)apf)[u];
                                      fb[u] = ((const float4*)bpf)[u]; }
        ushort ta[16], tb[16];
#pragma unroll
        for (int u = 0; u < 4; u++) {
            ta[u*4+0] = f2b(fa[u].x); ta[u*4+1] = f2b(fa[u].y);
            ta[u*4+2] = f2b(fa[u].z); ta[u*4+3] = f2b(fa[u].w);
            tb[u*4+0] = f2b(fb[u].x); tb[u*4+1] = f2b(fb[u].y);
            tb[u*4+2] = f2b(fb[u].z); tb[u*4+3] = f2b(fb[u].w);
        }
        __syncthreads();
        *(uint4*)&As[arow * 40 + ac]     = *(uint4*)&ta[0];
        *(uint4*)&As[arow * 40 + ac + 8] = *(uint4*)&ta[8];
        *(uint4*)&Bs[arow * 40 + ac]     = *(uint4*)&tb[0];
        *(uint4*)&Bs[arow * 40 + ac + 8] = *(uint4*)&tb[8];
        __syncthreads();
        bf16x8 af[4], bfr[4];
#pragma unroll
        for (int i = 0; i < 4; i++)
            af[i]  = *(bf16x8*)&As[(wm * 64 + i * 16 + ln) * 40 + quad * 8];
#pragma unroll
        for (int j = 0; j < 4; j++)
            bfr[j] = *(bf16x8*)&Bs[(wn * 64 + j * 16 + ln) * 40 + quad * 8];
#pragma unroll
        for (int i = 0; i < 4; i++)
#pragma unroll
            for (int j = 0; j < 4; j++)
                acc[i][j] = __builtin_amdgcn_mfma_f32_16x16x32_bf16(
                                af[i], bfr[j], acc[i][j], 0, 0, 0);
    }
}

// =====================================================================
// Kernel 1: fused QKV projection.  grid = (M/128, 3*8)
// q (PRE-SCALED by 1/8), k -> [B,H,N,D] bf16 in ws;
// v -> TRANSPOSED [B,H,D,N] bf16 in d_out scratch.
// =====================================================================
__global__ __launch_bounds__(256) void gemm_qkv(
        const float* __restrict__ x,
        const float* __restrict__ Wq, const float* __restrict__ Wk,
        const float* __restrict__ Wv,
        const float* __restrict__ bq, const float* __restrict__ bk,
        const float* __restrict__ bv,
        ushort* __restrict__ qb, ushort* __restrict__ kb,
        ushort* __restrict__ vT) {
    __shared__ short As[128 * 40];
    __shared__ short Bs[128 * 40];
    const int m0   = blockIdx.x * 128;
    const int nt   = blockIdx.y;           // 0..23
    const int wsel = nt >> 3;
    const int n0   = (nt & 7) * 128;
    const float* W    = (wsel == 0) ? Wq : (wsel == 1) ? Wk : Wv;
    const float* bias = (wsel == 0) ? bq : (wsel == 1) ? bk : bv;

    f32x4 acc[4][4];
    gemm_mainloop_1024(x, W, m0, n0, acc, As, Bs);

    const int t = threadIdx.x, lane = t & 63, wave = t >> 6;
    const int ln = lane & 15, quad = lane >> 4;
    const int wm = wave & 1, wn = wave >> 1;

    if (wsel < 2) {
        ushort* dst = (wsel == 0) ? qb : kb;
        const float scale = (wsel == 0) ? 0.125f : 1.0f;   // q pre-scaled
#pragma unroll
        for (int j = 0; j < 4; j++) {
            const int o  = n0 + wn * 64 + j * 16 + ln;     // output channel
            const float bval = bias[o];
            const int h = o >> 6, d = o & 63;
#pragma unroll
            for (int i = 0; i < 4; i++) {
                const int mg = m0 + wm * 64 + i * 16 + quad * 4;
#pragma unroll
                for (int r = 0; r < 4; r++) {
                    const int m  = mg + r;
                    const int b  = m >> 11;          // / 2048
                    const int ns = m & 2047;
                    dst[(size_t)(b * NH + h) * BHSTRIDE + (size_t)ns * HD + d] =
                        f2b((acc[i][j][r] + bval) * scale);
                }
            }
        }
    } else {
        // V transposed: vT[(b*NH+h)*BHSTRIDE + d*SEQN + n]
#pragma unroll
        for (int j = 0; j < 4; j++) {
            const int o  = n0 + wn * 64 + j * 16 + ln;
            const float bval = bias[o];
            const int h = o >> 6, d = o & 63;
#pragma unroll
            for (int i = 0; i < 4; i++) {
                const int mg = m0 + wm * 64 + i * 16 + quad * 4;
                const int b  = mg >> 11;
                const int ns = mg & 2047;           // 4-aligned, same batch
                ushort pk[4];
#pragma unroll
                for (int r = 0; r < 4; r++) pk[r] = f2b(acc[i][j][r] + bval);
                *(uint2*)&vT[(size_t)(b * NH + h) * BHSTRIDE +
                             (size_t)d * SEQN + ns] = *(uint2*)&pk[0];
            }
        }
    }
}

// =====================================================================
// Kernel 2: distance-biased attention with BLOCK-COOPERATIVE LDS
// staging of K/V tiles (m97-style 2-barrier K-loop, register-prefetched
// next tile).  grid = (N/128, H, B); 4 waves x 32 q-rows; kv-tile 64.
// K/V tiles loaded ONCE per block (coalesced 128B rows) instead of once
// per wave; fragments come from LDS (ds_read_b128, stride 72 shorts =
// 144B: 16B-aligned, conflict-free per quarter-wave).
// Bias via permuted E table (coalesced uint2).  Output in-place over q.
// q pre-scaled by 1/8 so p = E * exp(s).
// =====================================================================
__global__ __launch_bounds__(256) void attn(
        ushort* q,                     // aliased in/out (no restrict)
        const ushort* __restrict__ k,
        const ushort* __restrict__ vT,
        const ushort* __restrict__ E) {
    __shared__ short Ks[64 * 72];      // [kv][d]
    __shared__ short Vs[64 * 72];      // [d][kv]
    __shared__ short Ps[4][32 * 72];   // per-wave P tile [q-row][kv]
    const int t = threadIdx.x, lane = t & 63, wave = t >> 6;
    const int ln = lane & 15, quad = lane >> 4;
    const int h = blockIdx.y, b = blockIdx.z;
    const int bh = b * NH + h;
    const int qw0 = blockIdx.x * 128 + wave * 32;   // this wave's 32 q-rows
    const int qt0 = qw0 >> 4;                       // q-tile index for E

    ushort* qp = q + (size_t)bh * BHSTRIDE;
    const ushort* kp = k  + (size_t)bh * BHSTRIDE;
    const ushort* vp = vT + (size_t)bh * BHSTRIDE;

    // staging coords: thread t covers row sr, 16-short chunk sc
    const int sr = t >> 2;           // 0..63
    const int sc = (t & 3) * 16;     // 0,16,32,48

    // Q fragments (A-operand): registers for the whole kv loop
    bf16x8 qf[2][2];
#pragma unroll
    for (int qi = 0; qi < 2; qi++)
#pragma unroll
        for (int ks = 0; ks < 2; ks++)
            qf[qi][ks] = *(const bf16x8*)(qp + (size_t)(qw0 + qi * 16 + ln) * HD
                                          + ks * 32 + quad * 8);

    f32x4 O[2][4];
#pragma unroll
    for (int qi = 0; qi < 2; qi++)
#pragma unroll
        for (int nd = 0; nd < 4; nd++) O[qi][nd] = (f32x4){0.f, 0.f, 0.f, 0.f};
    float lsum[2][4] = {{0.f,0.f,0.f,0.f},{0.f,0.f,0.f,0.f}};
    short* myp = &Ps[wave][0];

    // ---- prologue: load tile 0 into staging registers ----
    uint4 krg0 = *(const uint4*)(kp + (size_t)sr * HD + sc);
    uint4 krg1 = *(const uint4*)(kp + (size_t)sr * HD + sc + 8);
    uint4 vrg0 = *(const uint4*)(vp + (size_t)sr * SEQN + sc);
    uint4 vrg1 = *(const uint4*)(vp + (size_t)sr * SEQN + sc + 8);

    for (int kt = 0; kt < 32; kt++) {
        const int kv0 = kt * 64;
        __syncthreads();             // prev iteration's LDS reads complete
        *(uint4*)&Ks[sr * 72 + sc]     = krg0;
        *(uint4*)&Ks[sr * 72 + sc + 8] = krg1;
        *(uint4*)&Vs[sr * 72 + sc]     = vrg0;
        *(uint4*)&Vs[sr * 72 + sc + 8] = vrg1;
        __syncthreads();             // tiles visible to all waves
        // ---- prefetch next tile (latency hides under compute below) ----
        const int kvn = (kv0 + 64) & 2047;   // wrap: last prefetch harmless
        krg0 = *(const uint4*)(kp + (size_t)(kvn + sr) * HD + sc);
        krg1 = *(const uint4*)(kp + (size_t)(kvn + sr) * HD + sc + 8);
        vrg0 = *(const uint4*)(vp + (size_t)sr * SEQN + kvn + sc);
        vrg1 = *(const uint4*)(vp + (size_t)sr * SEQN + kvn + sc + 8);
        // ---- E values (coalesced uint2 from permuted table) ----
        uint2 ev2[2][4];
#pragma unroll
        for (int qi = 0; qi < 2; qi++) {
            const size_t ebase = ((size_t)(qt0 + qi)) << 15;
#pragma unroll
            for (int kvb = 0; kvb < 4; kvb++)
                ev2[qi][kvb] = *(const uint2*)(E + ebase +
                    (size_t)(kv0 + kvb * 16 + ln) * 16 + quad * 4);
        }
        // ---- K fragments from LDS (shared across qi) ----
        bf16x8 kf0[4], kf1[4];
#pragma unroll
        for (int kvb = 0; kvb < 4; kvb++) {
            kf0[kvb] = *(bf16x8*)&Ks[(kvb * 16 + ln) * 72 + quad * 8];
            kf1[kvb] = *(bf16x8*)&Ks[(kvb * 16 + ln) * 72 + 32 + quad * 8];
        }
        // ---- S = Q K^T ----
        f32x4 s[2][4];
#pragma unroll
        for (int qi = 0; qi < 2; qi++)
#pragma unroll
            for (int kvb = 0; kvb < 4; kvb++) {
                f32x4 z = (f32x4){0.f, 0.f, 0.f, 0.f};
                z = __builtin_amdgcn_mfma_f32_16x16x32_bf16(qf[qi][0], kf0[kvb], z, 0, 0, 0);
                s[qi][kvb] = __builtin_amdgcn_mfma_f32_16x16x32_bf16(qf[qi][1], kf1[kvb], z, 0, 0, 0);
            }
        // ---- p = E * exp(s); pack to per-wave LDS (C -> A layout) ----
#pragma unroll
        for (int qi = 0; qi < 2; qi++)
#pragma unroll
            for (int kvb = 0; kvb < 4; kvb++) {
                const ushort* ep = (const ushort*)&ev2[qi][kvb];
#pragma unroll
                for (int r = 0; r < 4; r++) {
                    const float p = b2f(ep[r]) * __expf(s[qi][kvb][r]);
                    lsum[qi][r] += p;
                    myp[(qi * 16 + quad * 4 + r) * 72 + kvb * 16 + ln] =
                        (short)f2b_fast(p);
                }
            }
        // ---- V fragments from LDS ----
        bf16x8 vf[4][2];
#pragma unroll
        for (int nd = 0; nd < 4; nd++)
#pragma unroll
            for (int kc = 0; kc < 2; kc++)
                vf[nd][kc] = *(bf16x8*)&Vs[(nd * 16 + ln) * 72 + kc * 32 + quad * 8];
        // ---- P A-fragments (same-wave LDS round trip, in-order DS) ----
        bf16x8 pa[2][2];
#pragma unroll
        for (int qi = 0; qi < 2; qi++)
#pragma unroll
            for (int kc = 0; kc < 2; kc++)
                pa[qi][kc] = *(bf16x8*)&myp[(qi * 16 + ln) * 72 + kc * 32 + quad * 8];
        // ---- O += P V ----
#pragma unroll
        for (int qi = 0; qi < 2; qi++)
#pragma unroll
            for (int kc = 0; kc < 2; kc++)
#pragma unroll
                for (int nd = 0; nd < 4; nd++)
                    O[qi][nd] = __builtin_amdgcn_mfma_f32_16x16x32_bf16(
                                    pa[qi][kc], vf[nd][kc], O[qi][nd], 0, 0, 0);
    }

    // row-sum reduce across the 16 lanes of each quad-row group
#pragma unroll
    for (int qi = 0; qi < 2; qi++)
#pragma unroll
        for (int r = 0; r < 4; r++) {
            float v = lsum[qi][r];
            v += __shfl_xor(v, 1, 16);
            v += __shfl_xor(v, 2, 16);
            v += __shfl_xor(v, 4, 16);
            v += __shfl_xor(v, 8, 16);
            lsum[qi][r] = 1.0f / v;
        }
    // write output in-place over q, [B,H,N,D] layout
#pragma unroll
    for (int qi = 0; qi < 2; qi++)
#pragma unroll
        for (int nd = 0; nd < 4; nd++)
#pragma unroll
            for (int r = 0; r < 4; r++) {
                qp[(size_t)(qw0 + qi * 16 + quad * 4 + r) * HD + nd * 16 + ln] =
                    f2b(O[qi][nd][r] * lsum[qi][r]);
            }
}

// =====================================================================
// Kernel 3: output projection -> d_out.  grid = (M/128, 8)
// A = attn output stored [B,H,N,D] bf16 (internal); W/bias fp32.
// =====================================================================
__global__ __launch_bounds__(256) void gemm_out(
        const ushort* ao, const float* __restrict__ W,
        const float* __restrict__ bias, float* __restrict__ out) {
    __shared__ short As[128 * 40];
    __shared__ short Bs[128 * 40];
    const int m0 = blockIdx.x * 128;
    const int n0 = blockIdx.y * 128;
    const int t    = threadIdx.x;
    const int lane = t & 63;
    const int wave = t >> 6;
    const int ln   = lane & 15;
    const int quad = lane >> 4;
    const int wm   = wave & 1;
    const int wn   = wave >> 1;
    const int arow = t >> 1;
    const int ac   = (t & 1) * 16;

    const int mrow = m0 + arow;
    const int ab   = mrow >> 11;          // batch
    const int an   = mrow & 2047;         // seq pos
    const ushort* abase = ao + ((size_t)ab << 21) + (size_t)an * HD;

    f32x4 acc[4][4];
    for (int i = 0; i < 4; i++)
        for (int j = 0; j < 4; j++)
            acc[i][j] = (f32x4){0.f, 0.f, 0.f, 0.f};

    for (int k0 = 0; k0 < 1024; k0 += 32) {
        const int kk = k0 + ac;
        const int hh = kk >> 6, d0 = kk & 63;
        const ushort* ap = abase + ((size_t)hh << 17) + d0;
        uint4 sa0 = *(const uint4*)ap;
        uint4 sa1 = *(const uint4*)(ap + 8);
        const float* bpf = W + (size_t)(n0 + arow) * 1024 + kk;
        float4 fb[4];
#pragma unroll
        for (int u = 0; u < 4; u++) fb[u] = ((const float4*)bpf)[u];
        ushort tb[16];
#pragma unroll
        for (int u = 0; u < 4; u++) {
            tb[u*4+0] = f2b(fb[u].x); tb[u*4+1] = f2b(fb[u].y);
            tb[u*4+2] = f2b(fb[u].z); tb[u*4+3] = f2b(fb[u].w);
        }
        __syncthreads();
        *(uint4*)&As[arow * 40 + ac]     = sa0;
        *(uint4*)&As[arow * 40 + ac + 8] = sa1;
        *(uint4*)&Bs[arow * 40 + ac]     = *(uint4*)&tb[0];
        *(uint4*)&Bs[arow * 40 + ac + 8] = *(uint4*)&tb[8];
        __syncthreads();
        bf16x8 af[4], bfr[4];
#pragma unroll
        for (int i = 0; i < 4; i++)
            af[i]  = *(bf16x8*)&As[(wm * 64 + i * 16 + ln) * 40 + quad * 8];
#pragma unroll
        for (int j = 0; j < 4; j++)
            bfr[j] = *(bf16x8*)&Bs[(wn * 64 + j * 16 + ln) * 40 + quad * 8];
#pragma unroll
        for (int i = 0; i < 4; i++)
#pragma unroll
            for (int j = 0; j < 4; j++)
                acc[i][j] = __builtin_amdgcn_mfma_f32_16x16x32_bf16(
                                af[i], bfr[j], acc[i][j], 0, 0, 0);
    }

#pragma unroll
    for (int j = 0; j < 4; j++) {
        const int o = n0 + wn * 64 + j * 16 + ln;
        const float bval = bias[o];
#pragma unroll
        for (int i = 0; i < 4; i++) {
            const int mg = m0 + wm * 64 + i * 16 + quad * 4;
#pragma unroll
            for (int r = 0; r < 4; r++)
                out[(size_t)(mg + r) * EMB + o] = acc[i][j][r] + bval;
        }
    }
}

// =====================================================================
extern "C" void kernel_launch(void* const* d_in, const int* in_sizes, int n_in,
                              void* d_out, int out_size, void* d_ws, size_t ws_size,
                              hipStream_t stream) {
    const float* x    = (const float*)d_in[0];
    const float* dist = (const float*)d_in[1];
    const float* Wq   = (const float*)d_in[2];
    const float* bq   = (const float*)d_in[3];
    const float* Wk   = (const float*)d_in[4];
    const float* bk   = (const float*)d_in[5];
    const float* Wv   = (const float*)d_in[6];
    const float* bv   = (const float*)d_in[7];
    const float* Wo   = (const float*)d_in[8];
    const float* bo   = (const float*)d_in[9];
    const float* dw   = (const float*)d_in[10];
    const float* db   = (const float*)d_in[11];

    const size_t PLANE = (size_t)8192 * 1024;   // elems per [M,C] bf16 buffer
    ushort* qb = (ushort*)d_ws;                 // [B,H,N,D] bf16, later attn out
    ushort* kb = qb + PLANE;                    // [B,H,N,D] bf16
    // d_out is fp32 [8192,1024] = 33.6 MB; use as scratch before gemm_out:
    ushort* vT = (ushort*)d_out;                // [B,H,D,N] bf16 (16.8 MB)
    ushort* Eb = vT + PLANE;                    // permuted E table (8.4 MB)

    dim3 blk(256);
    bias_exp_perm<<<dim3(8, 128),   blk, 0, stream>>>(dist, dw, db, Eb);
    gemm_qkv     <<<dim3(64, 24),   blk, 0, stream>>>(x, Wq, Wk, Wv, bq, bk, bv,
                                                      qb, kb, vT);
    attn         <<<dim3(16, 16, 4), blk, 0, stream>>>(qb, kb, vT, Eb);
    gemm_out     <<<dim3(64, 8),    blk, 0, stream>>>(qb, Wo, bo, (float*)d_out);
}